// Round 1
// baseline (2894.810 us; speedup 1.0000x reference)
//
#include <hip/hip_runtime.h>

#define TT 8
#define NN 50000
#define DD 128
#define HH 128
#define MM 64
#define EE 800000

// ---------------- edge conversion (robust to int32/int64 harness layout) ---
__global__ __launch_bounds__(256) void kConvEdges(const int* __restrict__ eraw,
                                                  int* __restrict__ src,
                                                  int* __restrict__ tgt) {
    // int64 layout => hi words (odd int32 slots) of first values are 0
    bool is64 = true;
#pragma unroll
    for (int i = 0; i < 8; ++i)
        if (eraw[2 * i + 1] != 0) is64 = false;
    int i = blockIdx.x * blockDim.x + threadIdx.x;
    if (i < EE) {
        int s, t;
        if (is64) {
            const long long* e64 = (const long long*)eraw;
            s = (int)e64[i];
            t = (int)e64[EE + i];
        } else {
            s = eraw[i];
            t = eraw[EE + i];
        }
        s = min(max(s, 0), NN - 1);
        t = min(max(t, 0), NN - 1);
        src[i] = s;
        tgt[i] = t;
    }
}

// ---------------- kernel A: s = relu(X@Wsp+bsp); a = s@Wmp_top+bmp; q = s@Wmp_bot
// 8 nodes per 128-thread block; also zeroes msgq rows for this block.
__global__ __launch_bounds__(128) void kA(const float* __restrict__ X,
                                          const float* __restrict__ Wsp,
                                          const float* __restrict__ bsp,
                                          const float* __restrict__ Wmp,
                                          const float* __restrict__ bmp,
                                          float* __restrict__ a,
                                          float* __restrict__ q,
                                          float* __restrict__ msgq,
                                          float* __restrict__ s_last,
                                          int write_s) {
    __shared__ float xs[8][DD];
    __shared__ float ss[8][DD];
    const int j = threadIdx.x;
    const int base = blockIdx.x * 8;

#pragma unroll
    for (int n = 0; n < 8; ++n)
        xs[n][j] = X[(size_t)(base + n) * DD + j];
    __syncthreads();

    float acc[8];
    const float bj = bsp[j];
#pragma unroll
    for (int n = 0; n < 8; ++n) acc[n] = bj;
#pragma unroll 4
    for (int k = 0; k < DD; ++k) {
        float w = Wsp[k * HH + j];
#pragma unroll
        for (int n = 0; n < 8; ++n) acc[n] = fmaf(xs[n][k], w, acc[n]);
    }
#pragma unroll
    for (int n = 0; n < 8; ++n) {
        float s = fmaxf(acc[n], 0.f);
        ss[n][j] = s;
        if (write_s) s_last[(size_t)(base + n) * HH + j] = s;
    }
    __syncthreads();

    // phase 2: wave0 (j<64) -> a columns, wave1 -> q columns
    const bool isA = (j < MM);
    const int jj = isA ? j : (j - MM);
    const int wbase = isA ? 0 : (HH * MM);
    float acc2[8];
    const float init = isA ? bmp[jj] : 0.f;
#pragma unroll
    for (int n = 0; n < 8; ++n) acc2[n] = init;
#pragma unroll 4
    for (int k = 0; k < DD; ++k) {
        float w = Wmp[wbase + k * MM + jj];
#pragma unroll
        for (int n = 0; n < 8; ++n) acc2[n] = fmaf(ss[n][k], w, acc2[n]);
    }
#pragma unroll
    for (int n = 0; n < 8; ++n) {
        size_t g = (size_t)(base + n) * MM + jj;
        if (isA) a[g] = acc2[n];
        else     q[g] = acc2[n];
    }
    // zero msgq rows for these 8 nodes (runs before scatter on the stream)
    for (int idx = j; idx < 8 * MM; idx += 128)
        msgq[(size_t)base * MM + idx] = 0.f;
}

// ---------------- kernel B: msgq[tgt] += q[src], one wave per edge ---------
__global__ __launch_bounds__(256) void kB(const float* __restrict__ q,
                                          float* __restrict__ msgq,
                                          const int* __restrict__ src,
                                          const int* __restrict__ tgt) {
    const int lane = threadIdx.x & 63;
    const int wave = (blockIdx.x * blockDim.x + threadIdx.x) >> 6;
    const int nwaves = (gridDim.x * blockDim.x) >> 6;
    for (int e = wave; e < EE; e += nwaves) {
        int s = src[e];
        int t = tgt[e];
        float v = q[(size_t)s * MM + lane];
        atomicAdd(&msgq[(size_t)t * MM + lane], v);
    }
}

// ---------------- kernel C: GRU update, 8 nodes per 192-thread block -------
__global__ __launch_bounds__(192) void kC(const float* __restrict__ a,
                                          const float* __restrict__ msgq,
                                          const float* __restrict__ Wi,
                                          const float* __restrict__ bi,
                                          const float* __restrict__ Wh,
                                          const float* __restrict__ bhn,
                                          float* __restrict__ h) {
    __shared__ float mi[8][MM];
    __shared__ float hs[8][MM];
    __shared__ float gis[8][192];
    __shared__ float ghs[8][192];
    const int j = threadIdx.x;  // 0..191
    const int base = blockIdx.x * 8;

    for (int idx = j; idx < 8 * MM; idx += 192) {
        int n = idx >> 6, c = idx & 63;
        size_t g = (size_t)(base + n) * MM + c;
        mi[n][c] = a[g] + msgq[g];
        hs[n][c] = h[g];
    }
    __syncthreads();

    float gi[8], gh[8];
    const float bij = bi[j];
#pragma unroll
    for (int n = 0; n < 8; ++n) { gi[n] = bij; gh[n] = 0.f; }
#pragma unroll 2
    for (int k = 0; k < MM; ++k) {
        float wi = Wi[k * 192 + j];
        float wh = Wh[k * 192 + j];
#pragma unroll
        for (int n = 0; n < 8; ++n) {
            gi[n] = fmaf(mi[n][k], wi, gi[n]);
            gh[n] = fmaf(hs[n][k], wh, gh[n]);
        }
    }
#pragma unroll
    for (int n = 0; n < 8; ++n) { gis[n][j] = gi[n]; ghs[n][j] = gh[n]; }
    __syncthreads();

    for (int idx = j; idx < 8 * MM; idx += 192) {
        int n = idx >> 6, c = idx & 63;
        float xr = gis[n][c] + ghs[n][c];
        float xz = gis[n][64 + c] + ghs[n][64 + c];
        float r = 1.f / (1.f + __expf(-xr));
        float z = 1.f / (1.f + __expf(-xz));
        float xn = gis[n][128 + c] + r * (ghs[n][128 + c] + bhn[c]);
        float e2 = __expf(2.f * xn);
        float nn = 1.f - 2.f / (e2 + 1.f);  // tanh
        float hnew = (1.f - z) * nn + z * hs[n][c];
        h[(size_t)(base + n) * MM + c] = hnew;
    }
}

// ---------------- kernel D: out = [s,h]@Wout+bout; conv over feature axis --
__global__ __launch_bounds__(128) void kD(const float* __restrict__ s_last,
                                          const float* __restrict__ h,
                                          const float* __restrict__ Wout,
                                          const float* __restrict__ bout,
                                          const float* __restrict__ convk,
                                          const float* __restrict__ convb,
                                          float* __restrict__ out) {
    __shared__ float ss[4][HH];
    __shared__ float hs[4][MM];
    __shared__ float os[4][HH];
    const int j = threadIdx.x;
    const int base = blockIdx.x * 4;

#pragma unroll
    for (int n = 0; n < 4; ++n)
        ss[n][j] = s_last[(size_t)(base + n) * HH + j];
    for (int idx = j; idx < 4 * MM; idx += 128) {
        int n = idx >> 6, c = idx & 63;
        hs[n][c] = h[(size_t)(base + n) * MM + c];
    }
    __syncthreads();

    float acc[4];
    const float bj = bout[j];
#pragma unroll
    for (int n = 0; n < 4; ++n) acc[n] = bj;
#pragma unroll 4
    for (int k = 0; k < HH; ++k) {
        float w = Wout[k * HH + j];
#pragma unroll
        for (int n = 0; n < 4; ++n) acc[n] = fmaf(ss[n][k], w, acc[n]);
    }
#pragma unroll 4
    for (int k = 0; k < MM; ++k) {
        float w = Wout[(HH + k) * HH + j];
#pragma unroll
        for (int n = 0; n < 4; ++n) acc[n] = fmaf(hs[n][k], w, acc[n]);
    }
#pragma unroll
    for (int n = 0; n < 4; ++n) os[n][j] = acc[n];
    __syncthreads();

    // cross-correlation over the feature axis, kernel k0[i]=conv_k[i,0,0],
    // SAME padding: lo=4, hi=5; bias = conv_b[0]
    float ck[10];
#pragma unroll
    for (int i = 0; i < 10; ++i) ck[i] = convk[i * HH];
    const float cb = convb[0];
#pragma unroll
    for (int n = 0; n < 4; ++n) {
        float y = cb;
#pragma unroll
        for (int i = 0; i < 10; ++i) {
            int p = j - 4 + i;
            float xv = (p >= 0 && p < HH) ? os[n][p] : 0.f;
            y = fmaf(xv, ck[i], y);
        }
        out[(size_t)(base + n) * HH + j] = y;
    }
    // h_final appended after final (tuple concat order)
    for (int idx = j; idx < 4 * MM; idx += 128) {
        int n = idx >> 6, c = idx & 63;
        out[(size_t)NN * HH + (size_t)(base + n) * MM + c] = hs[n][c];
    }
}

extern "C" void kernel_launch(void* const* d_in, const int* in_sizes, int n_in,
                              void* d_out, int out_size, void* d_ws, size_t ws_size,
                              hipStream_t stream) {
    const float* X    = (const float*)d_in[0];
    const int*   eraw = (const int*)d_in[1];
    const float* Wsp  = (const float*)d_in[2];
    const float* bsp  = (const float*)d_in[3];
    const float* Wmp  = (const float*)d_in[4];
    const float* bmp  = (const float*)d_in[5];
    const float* Wi   = (const float*)d_in[6];
    const float* bi   = (const float*)d_in[7];
    const float* Wh   = (const float*)d_in[8];
    const float* bhn  = (const float*)d_in[9];
    const float* Wout = (const float*)d_in[10];
    const float* bout = (const float*)d_in[11];
    const float* ck   = (const float*)d_in[12];
    const float* cb   = (const float*)d_in[13];
    float* out = (float*)d_out;

    float* ws = (float*)d_ws;
    float* h      = ws;                       // N*M
    float* a      = ws + (size_t)NN * MM;     // N*M
    float* q      = a + (size_t)NN * MM;      // N*M
    float* msgq   = q + (size_t)NN * MM;      // N*M
    float* s_last = msgq + (size_t)NN * MM;   // N*H
    int*   src    = (int*)(s_last + (size_t)NN * HH);
    int*   tgt    = src + EE;

    hipMemsetAsync(h, 0, (size_t)NN * MM * sizeof(float), stream);
    kConvEdges<<<(EE + 255) / 256, 256, 0, stream>>>(eraw, src, tgt);

    for (int t = 0; t < TT; ++t) {
        kA<<<NN / 8, 128, 0, stream>>>(X + (size_t)t * NN * DD, Wsp, bsp, Wmp, bmp,
                                       a, q, msgq, s_last, (t == TT - 1) ? 1 : 0);
        kB<<<2048, 256, 0, stream>>>(q, msgq, src, tgt);
        kC<<<NN / 8, 192, 0, stream>>>(a, msgq, Wi, bi, Wh, bhn, h);
    }
    kD<<<NN / 4, 128, 0, stream>>>(s_last, h, Wout, bout, ck, cb, out);
}

// Round 2
// 2030.461 us; speedup vs baseline: 1.4257x; 1.4257x over previous
//
#include <hip/hip_runtime.h>

#define TT 8
#define NN 50000
#define DD 128
#define HH 128
#define MM 64
#define EE 800000
#define NBLK 196  // ceil(NN/256)

// ---------------- edge conversion + degree histogram ----------------------
__global__ __launch_bounds__(256) void kConvEdges(const int* __restrict__ eraw,
                                                  int* __restrict__ src,
                                                  int* __restrict__ tgt,
                                                  int* __restrict__ deg) {
    // int64 layout => hi words (odd int32 slots) of first values are 0
    bool is64 = true;
#pragma unroll
    for (int i = 0; i < 8; ++i)
        if (eraw[2 * i + 1] != 0) is64 = false;
    int i = blockIdx.x * blockDim.x + threadIdx.x;
    if (i < EE) {
        int s, t;
        if (is64) {
            const long long* e64 = (const long long*)eraw;
            s = (int)e64[i];
            t = (int)e64[EE + i];
        } else {
            s = eraw[i];
            t = eraw[EE + i];
        }
        s = min(max(s, 0), NN - 1);
        t = min(max(t, 0), NN - 1);
        src[i] = s;
        tgt[i] = t;
        atomicAdd(&deg[t], 1);
    }
}

// ---------------- hierarchical exclusive scan of deg -> rowptr ------------
__global__ __launch_bounds__(256) void kScanA(const int* __restrict__ deg,
                                              int* __restrict__ itmp,
                                              int* __restrict__ bsum) {
    __shared__ int sm[256];
    int gid = blockIdx.x * 256 + threadIdx.x;
    int v = (gid < NN) ? deg[gid] : 0;
    sm[threadIdx.x] = v;
    __syncthreads();
    for (int off = 1; off < 256; off <<= 1) {
        int add = (threadIdx.x >= off) ? sm[threadIdx.x - off] : 0;
        __syncthreads();
        sm[threadIdx.x] += add;
        __syncthreads();
    }
    itmp[gid] = sm[threadIdx.x];
    if (threadIdx.x == 255) bsum[blockIdx.x] = sm[255];
}

__global__ __launch_bounds__(256) void kScanB(const int* __restrict__ bsum,
                                              int* __restrict__ boffs) {
    __shared__ int sm[256];
    int v = (threadIdx.x < NBLK) ? bsum[threadIdx.x] : 0;
    sm[threadIdx.x] = v;
    __syncthreads();
    for (int off = 1; off < 256; off <<= 1) {
        int add = (threadIdx.x >= off) ? sm[threadIdx.x - off] : 0;
        __syncthreads();
        sm[threadIdx.x] += add;
        __syncthreads();
    }
    if (threadIdx.x < NBLK)
        boffs[threadIdx.x] = (threadIdx.x == 0) ? 0 : sm[threadIdx.x - 1];
}

__global__ __launch_bounds__(256) void kScanC(const int* __restrict__ itmp,
                                              const int* __restrict__ boffs,
                                              int* __restrict__ rowptr) {
    int gid = blockIdx.x * 256 + threadIdx.x;
    if (gid < NN) rowptr[gid + 1] = itmp[gid] + boffs[blockIdx.x];
    if (gid == 0) rowptr[0] = 0;
}

// ---------------- CSR fill -------------------------------------------------
__global__ __launch_bounds__(256) void kFill(const int* __restrict__ src,
                                             const int* __restrict__ tgt,
                                             const int* __restrict__ rowptr,
                                             int* __restrict__ cursor,
                                             int* __restrict__ csr_src) {
    int e = blockIdx.x * blockDim.x + threadIdx.x;
    if (e < EE) {
        int t = tgt[e];
        int p = atomicAdd(&cursor[t], 1);
        csr_src[rowptr[t] + p] = src[e];
    }
}

// ---------------- kernel A: s = relu(X@Wsp+bsp); a = s@Wmp_top+bmp; q = s@Wmp_bot
__global__ __launch_bounds__(128) void kA(const float* __restrict__ X,
                                          const float* __restrict__ Wsp,
                                          const float* __restrict__ bsp,
                                          const float* __restrict__ Wmp,
                                          const float* __restrict__ bmp,
                                          float* __restrict__ a,
                                          float* __restrict__ q,
                                          float* __restrict__ s_last,
                                          int write_s) {
    __shared__ float xs[8][DD];
    __shared__ float ss[8][DD];
    const int j = threadIdx.x;
    const int base = blockIdx.x * 8;

#pragma unroll
    for (int n = 0; n < 8; ++n)
        xs[n][j] = X[(size_t)(base + n) * DD + j];
    __syncthreads();

    float acc[8];
    const float bj = bsp[j];
#pragma unroll
    for (int n = 0; n < 8; ++n) acc[n] = bj;
#pragma unroll 4
    for (int k = 0; k < DD; ++k) {
        float w = Wsp[k * HH + j];
#pragma unroll
        for (int n = 0; n < 8; ++n) acc[n] = fmaf(xs[n][k], w, acc[n]);
    }
#pragma unroll
    for (int n = 0; n < 8; ++n) {
        float s = fmaxf(acc[n], 0.f);
        ss[n][j] = s;
        if (write_s) s_last[(size_t)(base + n) * HH + j] = s;
    }
    __syncthreads();

    const bool isA = (j < MM);
    const int jj = isA ? j : (j - MM);
    const int wbase = isA ? 0 : (HH * MM);
    float acc2[8];
    const float init = isA ? bmp[jj] : 0.f;
#pragma unroll
    for (int n = 0; n < 8; ++n) acc2[n] = init;
#pragma unroll 4
    for (int k = 0; k < DD; ++k) {
        float w = Wmp[wbase + k * MM + jj];
#pragma unroll
        for (int n = 0; n < 8; ++n) acc2[n] = fmaf(ss[n][k], w, acc2[n]);
    }
#pragma unroll
    for (int n = 0; n < 8; ++n) {
        size_t g = (size_t)(base + n) * MM + jj;
        if (isA) a[g] = acc2[n];
        else     q[g] = acc2[n];
    }
}

// ---------------- kernel B2: msgq[n] = sum over in-edges of q[src] --------
__global__ __launch_bounds__(256) void kGather(const float* __restrict__ q,
                                               const int* __restrict__ rowptr,
                                               const int* __restrict__ csr_src,
                                               float* __restrict__ msgq) {
    const int lane = threadIdx.x & 63;
    const int w = (blockIdx.x * blockDim.x + threadIdx.x) >> 6;
    if (w >= NN) return;
    const int beg = rowptr[w];
    const int end = rowptr[w + 1];
    float acc0 = 0.f, acc1 = 0.f;
    int i = beg;
    for (; i + 1 < end; i += 2) {
        int s0 = csr_src[i];
        int s1 = csr_src[i + 1];
        acc0 += q[(size_t)s0 * MM + lane];
        acc1 += q[(size_t)s1 * MM + lane];
    }
    if (i < end) {
        int s0 = csr_src[i];
        acc0 += q[(size_t)s0 * MM + lane];
    }
    msgq[(size_t)w * MM + lane] = acc0 + acc1;
}

// ---------------- kernel C: GRU update, 8 nodes per 192-thread block -------
__global__ __launch_bounds__(192) void kC(const float* __restrict__ a,
                                          const float* __restrict__ msgq,
                                          const float* __restrict__ Wi,
                                          const float* __restrict__ bi,
                                          const float* __restrict__ Wh,
                                          const float* __restrict__ bhn,
                                          float* __restrict__ h) {
    __shared__ float mi[8][MM];
    __shared__ float hs[8][MM];
    __shared__ float gis[8][192];
    __shared__ float ghs[8][192];
    const int j = threadIdx.x;  // 0..191
    const int base = blockIdx.x * 8;

    for (int idx = j; idx < 8 * MM; idx += 192) {
        int n = idx >> 6, c = idx & 63;
        size_t g = (size_t)(base + n) * MM + c;
        mi[n][c] = a[g] + msgq[g];
        hs[n][c] = h[g];
    }
    __syncthreads();

    float gi[8], gh[8];
    const float bij = bi[j];
#pragma unroll
    for (int n = 0; n < 8; ++n) { gi[n] = bij; gh[n] = 0.f; }
#pragma unroll 2
    for (int k = 0; k < MM; ++k) {
        float wi = Wi[k * 192 + j];
        float wh = Wh[k * 192 + j];
#pragma unroll
        for (int n = 0; n < 8; ++n) {
            gi[n] = fmaf(mi[n][k], wi, gi[n]);
            gh[n] = fmaf(hs[n][k], wh, gh[n]);
        }
    }
#pragma unroll
    for (int n = 0; n < 8; ++n) { gis[n][j] = gi[n]; ghs[n][j] = gh[n]; }
    __syncthreads();

    for (int idx = j; idx < 8 * MM; idx += 192) {
        int n = idx >> 6, c = idx & 63;
        float xr = gis[n][c] + ghs[n][c];
        float xz = gis[n][64 + c] + ghs[n][64 + c];
        float r = 1.f / (1.f + __expf(-xr));
        float z = 1.f / (1.f + __expf(-xz));
        float xn = gis[n][128 + c] + r * (ghs[n][128 + c] + bhn[c]);
        float e2 = __expf(2.f * xn);
        float nn = 1.f - 2.f / (e2 + 1.f);  // tanh
        float hnew = (1.f - z) * nn + z * hs[n][c];
        h[(size_t)(base + n) * MM + c] = hnew;
    }
}

// ---------------- kernel D: out = [s,h]@Wout+bout; conv over feature axis --
__global__ __launch_bounds__(128) void kD(const float* __restrict__ s_last,
                                          const float* __restrict__ h,
                                          const float* __restrict__ Wout,
                                          const float* __restrict__ bout,
                                          const float* __restrict__ convk,
                                          const float* __restrict__ convb,
                                          float* __restrict__ out) {
    __shared__ float ss[4][HH];
    __shared__ float hs[4][MM];
    __shared__ float os[4][HH];
    const int j = threadIdx.x;
    const int base = blockIdx.x * 4;

#pragma unroll
    for (int n = 0; n < 4; ++n)
        ss[n][j] = s_last[(size_t)(base + n) * HH + j];
    for (int idx = j; idx < 4 * MM; idx += 128) {
        int n = idx >> 6, c = idx & 63;
        hs[n][c] = h[(size_t)(base + n) * MM + c];
    }
    __syncthreads();

    float acc[4];
    const float bj = bout[j];
#pragma unroll
    for (int n = 0; n < 4; ++n) acc[n] = bj;
#pragma unroll 4
    for (int k = 0; k < HH; ++k) {
        float w = Wout[k * HH + j];
#pragma unroll
        for (int n = 0; n < 4; ++n) acc[n] = fmaf(ss[n][k], w, acc[n]);
    }
#pragma unroll 4
    for (int k = 0; k < MM; ++k) {
        float w = Wout[(HH + k) * HH + j];
#pragma unroll
        for (int n = 0; n < 4; ++n) acc[n] = fmaf(hs[n][k], w, acc[n]);
    }
#pragma unroll
    for (int n = 0; n < 4; ++n) os[n][j] = acc[n];
    __syncthreads();

    float ck[10];
#pragma unroll
    for (int i = 0; i < 10; ++i) ck[i] = convk[i * HH];
    const float cb = convb[0];
#pragma unroll
    for (int n = 0; n < 4; ++n) {
        float y = cb;
#pragma unroll
        for (int i = 0; i < 10; ++i) {
            int p = j - 4 + i;
            float xv = (p >= 0 && p < HH) ? os[n][p] : 0.f;
            y = fmaf(xv, ck[i], y);
        }
        out[(size_t)(base + n) * HH + j] = y;
    }
    for (int idx = j; idx < 4 * MM; idx += 128) {
        int n = idx >> 6, c = idx & 63;
        out[(size_t)NN * HH + (size_t)(base + n) * MM + c] = hs[n][c];
    }
}

extern "C" void kernel_launch(void* const* d_in, const int* in_sizes, int n_in,
                              void* d_out, int out_size, void* d_ws, size_t ws_size,
                              hipStream_t stream) {
    const float* X    = (const float*)d_in[0];
    const int*   eraw = (const int*)d_in[1];
    const float* Wsp  = (const float*)d_in[2];
    const float* bsp  = (const float*)d_in[3];
    const float* Wmp  = (const float*)d_in[4];
    const float* bmp  = (const float*)d_in[5];
    const float* Wi   = (const float*)d_in[6];
    const float* bi   = (const float*)d_in[7];
    const float* Wh   = (const float*)d_in[8];
    const float* bhn  = (const float*)d_in[9];
    const float* Wout = (const float*)d_in[10];
    const float* bout = (const float*)d_in[11];
    const float* ck   = (const float*)d_in[12];
    const float* cb   = (const float*)d_in[13];
    float* out = (float*)d_out;

    float* ws = (float*)d_ws;
    float* h      = ws;                        // N*M
    float* a      = h + (size_t)NN * MM;       // N*M
    float* q      = a + (size_t)NN * MM;       // N*M
    float* msgq   = q + (size_t)NN * MM;       // N*M
    float* s_last = msgq + (size_t)NN * MM;    // N*H
    int*   src     = (int*)(s_last + (size_t)NN * HH);
    int*   tgt     = src + EE;
    int*   csr_src = tgt + EE;
    int*   deg     = csr_src + EE;             // N
    int*   rowptr  = deg + NN;                 // N+1
    int*   cursor  = rowptr + NN + 1;          // N
    int*   itmp    = cursor + NN;              // NBLK*256
    int*   bsum    = itmp + NBLK * 256;        // 256
    int*   boffs   = bsum + 256;               // 256

    hipMemsetAsync(h, 0, (size_t)NN * MM * sizeof(float), stream);
    hipMemsetAsync(deg, 0, NN * sizeof(int), stream);
    hipMemsetAsync(cursor, 0, NN * sizeof(int), stream);

    kConvEdges<<<(EE + 255) / 256, 256, 0, stream>>>(eraw, src, tgt, deg);
    kScanA<<<NBLK, 256, 0, stream>>>(deg, itmp, bsum);
    kScanB<<<1, 256, 0, stream>>>(bsum, boffs);
    kScanC<<<NBLK, 256, 0, stream>>>(itmp, boffs, rowptr);
    kFill<<<(EE + 255) / 256, 256, 0, stream>>>(src, tgt, rowptr, cursor, csr_src);

    for (int t = 0; t < TT; ++t) {
        kA<<<NN / 8, 128, 0, stream>>>(X + (size_t)t * NN * DD, Wsp, bsp, Wmp, bmp,
                                       a, q, s_last, (t == TT - 1) ? 1 : 0);
        kGather<<<(NN * 64 + 255) / 256, 256, 0, stream>>>(q, rowptr, csr_src, msgq);
        kC<<<NN / 8, 192, 0, stream>>>(a, msgq, Wi, bi, Wh, bhn, h);
    }
    kD<<<NN / 4, 128, 0, stream>>>(s_last, h, Wout, bout, ck, cb, out);
}

// Round 3
// 1811.785 us; speedup vs baseline: 1.5978x; 1.1207x over previous
//
#include <hip/hip_runtime.h>

#define TT 8
#define NN 50000
#define DD 128
#define HH 128
#define MM 64
#define EE 800000
#define NBLK 196  // ceil(NN/256)

// ---------------- edge conversion + degree histogram ----------------------
__global__ __launch_bounds__(256) void kConvEdges(const int* __restrict__ eraw,
                                                  int* __restrict__ src,
                                                  int* __restrict__ tgt,
                                                  int* __restrict__ deg) {
    bool is64 = true;
#pragma unroll
    for (int i = 0; i < 8; ++i)
        if (eraw[2 * i + 1] != 0) is64 = false;
    int i = blockIdx.x * blockDim.x + threadIdx.x;
    if (i < EE) {
        int s, t;
        if (is64) {
            const long long* e64 = (const long long*)eraw;
            s = (int)e64[i];
            t = (int)e64[EE + i];
        } else {
            s = eraw[i];
            t = eraw[EE + i];
        }
        s = min(max(s, 0), NN - 1);
        t = min(max(t, 0), NN - 1);
        src[i] = s;
        tgt[i] = t;
        atomicAdd(&deg[t], 1);
    }
}

// ---------------- hierarchical exclusive scan of deg -> rowptr ------------
__global__ __launch_bounds__(256) void kScanA(const int* __restrict__ deg,
                                              int* __restrict__ itmp,
                                              int* __restrict__ bsum) {
    __shared__ int sm[256];
    int gid = blockIdx.x * 256 + threadIdx.x;
    int v = (gid < NN) ? deg[gid] : 0;
    sm[threadIdx.x] = v;
    __syncthreads();
    for (int off = 1; off < 256; off <<= 1) {
        int add = (threadIdx.x >= off) ? sm[threadIdx.x - off] : 0;
        __syncthreads();
        sm[threadIdx.x] += add;
        __syncthreads();
    }
    itmp[gid] = sm[threadIdx.x];
    if (threadIdx.x == 255) bsum[blockIdx.x] = sm[255];
}

__global__ __launch_bounds__(256) void kScanB(const int* __restrict__ bsum,
                                              int* __restrict__ boffs) {
    __shared__ int sm[256];
    int v = (threadIdx.x < NBLK) ? bsum[threadIdx.x] : 0;
    sm[threadIdx.x] = v;
    __syncthreads();
    for (int off = 1; off < 256; off <<= 1) {
        int add = (threadIdx.x >= off) ? sm[threadIdx.x - off] : 0;
        __syncthreads();
        sm[threadIdx.x] += add;
        __syncthreads();
    }
    if (threadIdx.x < NBLK)
        boffs[threadIdx.x] = (threadIdx.x == 0) ? 0 : sm[threadIdx.x - 1];
}

__global__ __launch_bounds__(256) void kScanC(const int* __restrict__ itmp,
                                              const int* __restrict__ boffs,
                                              int* __restrict__ rowptr) {
    int gid = blockIdx.x * 256 + threadIdx.x;
    if (gid < NN) rowptr[gid + 1] = itmp[gid] + boffs[blockIdx.x];
    if (gid == 0) rowptr[0] = 0;
}

// ---------------- CSR fill -------------------------------------------------
__global__ __launch_bounds__(256) void kFill(const int* __restrict__ src,
                                             const int* __restrict__ tgt,
                                             const int* __restrict__ rowptr,
                                             int* __restrict__ cursor,
                                             int* __restrict__ csr_src) {
    int e = blockIdx.x * blockDim.x + threadIdx.x;
    if (e < EE) {
        int t = tgt[e];
        int p = atomicAdd(&cursor[t], 1);
        csr_src[rowptr[t] + p] = src[e];
    }
}

// ---------------- weight repack: B2, Wgru, bias_aq, bias_g ----------------
__global__ __launch_bounds__(256) void kPrep(const float* __restrict__ Wmp,
                                             const float* __restrict__ bmp,
                                             const float* __restrict__ Wi,
                                             const float* __restrict__ bi,
                                             const float* __restrict__ Wh,
                                             const float* __restrict__ bhn,
                                             float* __restrict__ B2,
                                             float* __restrict__ Wgru,
                                             float* __restrict__ bias_aq,
                                             float* __restrict__ bias_g) {
    const int tid = threadIdx.x;
    // B2[128][128]: cols 0-63 = Wmp rows 0-127 (a); cols 64-127 = Wmp rows 128-255 (q)
    for (int i = tid; i < 128 * 128; i += 256) {
        int k = i >> 7, c = i & 127;
        B2[i] = (c < 64) ? Wmp[k * 64 + c] : Wmp[(128 + k) * 64 + (c - 64)];
    }
    // Wgru[128][256]: A = [mi | h]
    for (int i = tid; i < 128 * 256; i += 256) {
        int k = i >> 8, c = i & 255;
        float v;
        if (k < 64) {
            v = (c < 192) ? Wi[k * 192 + c] : 0.f;
        } else {
            int kk = k - 64;
            if (c < 128)      v = Wh[kk * 192 + c];
            else if (c < 192) v = 0.f;
            else              v = Wh[kk * 192 + (c - 64)];  // Wh[kk][128 + (c-192)]
        }
        Wgru[i] = v;
    }
    if (tid < 128) bias_aq[tid] = (tid < 64) ? bmp[tid] : 0.f;
    if (tid < 256) bias_g[tid] = (tid < 192) ? bi[tid] : bhn[tid - 192];
}

// ---------------- register-tiled fp32 GEMM: C[N x ldb] = A[N x 128] @ B ---
// block tile 64 rows x 128 cols, 256 threads, thread tile 4x(4+4)
__global__ __launch_bounds__(256) void kGemm(const float* __restrict__ A,
                                             const float* __restrict__ B,
                                             const float* __restrict__ bias,
                                             float* __restrict__ C,
                                             int ldb, int relu) {
    __shared__ float ATs[32][64];
    __shared__ float Ws[32][128];
    const int tid = threadIdx.x;
    const int tx = tid & 15, ty = tid >> 4;
    const int tm0 = ty * 4, tn0 = tx * 4;
    const int rowBase = blockIdx.x * 64;
    const int colBase = blockIdx.y * 128;

    float acc[4][8];
#pragma unroll
    for (int m = 0; m < 4; ++m)
#pragma unroll
        for (int n = 0; n < 8; ++n) acc[m][n] = 0.f;

    const int an = tid & 63, kq = tid >> 6;
    const int arow = min(rowBase + an, NN - 1);
    const float* Abase = &A[(size_t)arow * 128];

    for (int kt = 0; kt < 4; ++kt) {
        const int k0 = kt * 32;
        float4 a0 = *(const float4*)&Abase[k0 + kq * 8];
        float4 a1 = *(const float4*)&Abase[k0 + kq * 8 + 4];
        ATs[kq * 8 + 0][an] = a0.x;
        ATs[kq * 8 + 1][an] = a0.y;
        ATs[kq * 8 + 2][an] = a0.z;
        ATs[kq * 8 + 3][an] = a0.w;
        ATs[kq * 8 + 4][an] = a1.x;
        ATs[kq * 8 + 5][an] = a1.y;
        ATs[kq * 8 + 6][an] = a1.z;
        ATs[kq * 8 + 7][an] = a1.w;
#pragma unroll
        for (int r = 0; r < 4; ++r) {
            int idx = (r * 256 + tid) * 4;
            int kk = idx >> 7, cc = idx & 127;
            *(float4*)&Ws[kk][cc] =
                *(const float4*)&B[(size_t)(k0 + kk) * ldb + colBase + cc];
        }
        __syncthreads();
#pragma unroll 8
        for (int k = 0; k < 32; ++k) {
            float4 av = *(const float4*)&ATs[k][tm0];
            float4 b0 = *(const float4*)&Ws[k][tn0];
            float4 b1 = *(const float4*)&Ws[k][tn0 + 64];
            float am[4] = {av.x, av.y, av.z, av.w};
            float bn[8] = {b0.x, b0.y, b0.z, b0.w, b1.x, b1.y, b1.z, b1.w};
#pragma unroll
            for (int m = 0; m < 4; ++m)
#pragma unroll
                for (int n = 0; n < 8; ++n)
                    acc[m][n] = fmaf(am[m], bn[n], acc[m][n]);
        }
        __syncthreads();
    }

    float4 bi0 = *(const float4*)&bias[colBase + tn0];
    float4 bi1 = *(const float4*)&bias[colBase + 64 + tn0];
    float bb[8] = {bi0.x, bi0.y, bi0.z, bi0.w, bi1.x, bi1.y, bi1.z, bi1.w};
#pragma unroll
    for (int m = 0; m < 4; ++m) {
        int row = rowBase + tm0 + m;
        if (row < NN) {
            float o[8];
#pragma unroll
            for (int n = 0; n < 8; ++n) {
                float v = acc[m][n] + bb[n];
                o[n] = relu ? fmaxf(v, 0.f) : v;
            }
            float4 v0 = {o[0], o[1], o[2], o[3]};
            float4 v1 = {o[4], o[5], o[6], o[7]};
            *(float4*)&C[(size_t)row * ldb + colBase + tn0] = v0;
            *(float4*)&C[(size_t)row * ldb + colBase + 64 + tn0] = v1;
        }
    }
}

// ---------------- gather: mih[:, :64] = a + sum q[src] --------------------
__global__ __launch_bounds__(256) void kGather(const float* __restrict__ aq,
                                               const int* __restrict__ rowptr,
                                               const int* __restrict__ csr_src,
                                               float* __restrict__ mih) {
    const int lane = threadIdx.x & 63;
    const int w = (blockIdx.x * blockDim.x + threadIdx.x) >> 6;
    if (w >= NN) return;
    const int beg = rowptr[w];
    const int end = rowptr[w + 1];
    float acc0 = 0.f, acc1 = 0.f;
    int i = beg;
    for (; i + 1 < end; i += 2) {
        int s0 = csr_src[i];
        int s1 = csr_src[i + 1];
        acc0 += aq[(size_t)s0 * 128 + 64 + lane];
        acc1 += aq[(size_t)s1 * 128 + 64 + lane];
    }
    if (i < end) acc0 += aq[(size_t)csr_src[i] * 128 + 64 + lane];
    mih[(size_t)w * 128 + lane] = acc0 + acc1 + aq[(size_t)w * 128 + lane];
}

// ---------------- GRU epilogue: h' into mih[:, 64:] -----------------------
__global__ __launch_bounds__(256) void kCe(const float* __restrict__ g,
                                           float* __restrict__ mih) {
    int idx = blockIdx.x * 256 + threadIdx.x;  // one float4 (4 cols) per thread
    if (idx >= NN * 16) return;
    int node = idx >> 4;
    int cg = (idx & 15) * 4;
    const float* gr = &g[(size_t)node * 256];
    float4 g0 = *(const float4*)&gr[cg];
    float4 g1 = *(const float4*)&gr[64 + cg];
    float4 g2 = *(const float4*)&gr[128 + cg];
    float4 g3 = *(const float4*)&gr[192 + cg];
    float* hp = &mih[(size_t)node * 128 + 64 + cg];
    float4 hv = *(const float4*)hp;
    float xr[4] = {g0.x, g0.y, g0.z, g0.w};
    float xz[4] = {g1.x, g1.y, g1.z, g1.w};
    float xni[4] = {g2.x, g2.y, g2.z, g2.w};
    float xnh[4] = {g3.x, g3.y, g3.z, g3.w};
    float hh[4] = {hv.x, hv.y, hv.z, hv.w};
    float ho[4];
#pragma unroll
    for (int c = 0; c < 4; ++c) {
        float r = 1.f / (1.f + __expf(-xr[c]));
        float z = 1.f / (1.f + __expf(-xz[c]));
        float xn = xni[c] + r * xnh[c];
        float e2 = __expf(2.f * xn);
        float nn = 1.f - 2.f / (e2 + 1.f);
        ho[c] = (1.f - z) * nn + z * hh[c];
    }
    float4 hw = {ho[0], ho[1], ho[2], ho[3]};
    *(float4*)hp = hw;
}

// ---------------- kernel D: out = [s,h]@Wout+bout; conv over feature axis --
__global__ __launch_bounds__(128) void kD(const float* __restrict__ s_buf,
                                          const float* __restrict__ mih,
                                          const float* __restrict__ Wout,
                                          const float* __restrict__ bout,
                                          const float* __restrict__ convk,
                                          const float* __restrict__ convb,
                                          float* __restrict__ out) {
    __shared__ float ss[4][HH];
    __shared__ float hs[4][MM];
    __shared__ float os[4][HH];
    const int j = threadIdx.x;
    const int base = blockIdx.x * 4;

#pragma unroll
    for (int n = 0; n < 4; ++n)
        ss[n][j] = s_buf[(size_t)(base + n) * HH + j];
    for (int idx = j; idx < 4 * MM; idx += 128) {
        int n = idx >> 6, c = idx & 63;
        hs[n][c] = mih[(size_t)(base + n) * 128 + 64 + c];
    }
    __syncthreads();

    float acc[4];
    const float bj = bout[j];
#pragma unroll
    for (int n = 0; n < 4; ++n) acc[n] = bj;
#pragma unroll 4
    for (int k = 0; k < HH; ++k) {
        float w = Wout[k * HH + j];
#pragma unroll
        for (int n = 0; n < 4; ++n) acc[n] = fmaf(ss[n][k], w, acc[n]);
    }
#pragma unroll 4
    for (int k = 0; k < MM; ++k) {
        float w = Wout[(HH + k) * HH + j];
#pragma unroll
        for (int n = 0; n < 4; ++n) acc[n] = fmaf(hs[n][k], w, acc[n]);
    }
#pragma unroll
    for (int n = 0; n < 4; ++n) os[n][j] = acc[n];
    __syncthreads();

    float ck[10];
#pragma unroll
    for (int i = 0; i < 10; ++i) ck[i] = convk[i * HH];
    const float cb = convb[0];
#pragma unroll
    for (int n = 0; n < 4; ++n) {
        float y = cb;
#pragma unroll
        for (int i = 0; i < 10; ++i) {
            int p = j - 4 + i;
            float xv = (p >= 0 && p < HH) ? os[n][p] : 0.f;
            y = fmaf(xv, ck[i], y);
        }
        out[(size_t)(base + n) * HH + j] = y;
    }
    for (int idx = j; idx < 4 * MM; idx += 128) {
        int n = idx >> 6, c = idx & 63;
        out[(size_t)NN * HH + (size_t)(base + n) * MM + c] = hs[n][c];
    }
}

extern "C" void kernel_launch(void* const* d_in, const int* in_sizes, int n_in,
                              void* d_out, int out_size, void* d_ws, size_t ws_size,
                              hipStream_t stream) {
    const float* X    = (const float*)d_in[0];
    const int*   eraw = (const int*)d_in[1];
    const float* Wsp  = (const float*)d_in[2];
    const float* bsp  = (const float*)d_in[3];
    const float* Wmp  = (const float*)d_in[4];
    const float* bmp  = (const float*)d_in[5];
    const float* Wi   = (const float*)d_in[6];
    const float* bi   = (const float*)d_in[7];
    const float* Wh   = (const float*)d_in[8];
    const float* bhn  = (const float*)d_in[9];
    const float* Wout = (const float*)d_in[10];
    const float* bout = (const float*)d_in[11];
    const float* ck   = (const float*)d_in[12];
    const float* cb   = (const float*)d_in[13];
    float* out = (float*)d_out;

    float* ws = (float*)d_ws;
    float* s_buf  = ws;                         // N*128
    float* aq     = s_buf + (size_t)NN * 128;   // N*128
    float* mih    = aq + (size_t)NN * 128;      // N*128  ([a+msg | h])
    float* g      = mih + (size_t)NN * 128;     // N*256
    float* B2     = g + (size_t)NN * 256;       // 128*128
    float* Wgru   = B2 + 128 * 128;             // 128*256
    float* bias_aq= Wgru + 128 * 256;           // 128
    float* bias_g = bias_aq + 128;              // 256
    int*   src     = (int*)(bias_g + 256);
    int*   tgt     = src + EE;
    int*   csr_src = tgt + EE;
    int*   deg     = csr_src + EE;              // N
    int*   rowptr  = deg + NN;                  // N+1
    int*   cursor  = rowptr + NN + 1;           // N
    int*   itmp    = cursor + NN;               // NBLK*256
    int*   bsum    = itmp + NBLK * 256;         // 256
    int*   boffs   = bsum + 256;                // 256

    hipMemsetAsync(mih, 0, (size_t)NN * 128 * sizeof(float), stream);  // h0 = 0
    hipMemsetAsync(deg, 0, NN * sizeof(int), stream);
    hipMemsetAsync(cursor, 0, NN * sizeof(int), stream);

    kConvEdges<<<(EE + 255) / 256, 256, 0, stream>>>(eraw, src, tgt, deg);
    kScanA<<<NBLK, 256, 0, stream>>>(deg, itmp, bsum);
    kScanB<<<1, 256, 0, stream>>>(bsum, boffs);
    kScanC<<<NBLK, 256, 0, stream>>>(itmp, boffs, rowptr);
    kFill<<<(EE + 255) / 256, 256, 0, stream>>>(src, tgt, rowptr, cursor, csr_src);
    kPrep<<<1, 256, 0, stream>>>(Wmp, bmp, Wi, bi, Wh, bhn, B2, Wgru, bias_aq, bias_g);

    const int gx = (NN + 63) / 64;  // 782
    for (int t = 0; t < TT; ++t) {
        // s = relu(X_t @ Wsp + bsp)
        kGemm<<<dim3(gx, 1), 256, 0, stream>>>(X + (size_t)t * NN * DD, Wsp, bsp,
                                               s_buf, 128, 1);
        // aq = s @ B2 + bias_aq   (cols 0-63 = a, 64-127 = q)
        kGemm<<<dim3(gx, 1), 256, 0, stream>>>(s_buf, B2, bias_aq, aq, 128, 0);
        // mih[:, :64] = a + scatter-sum(q)
        kGather<<<(NN * 64 + 255) / 256, 256, 0, stream>>>(aq, rowptr, csr_src, mih);
        // g = mih @ Wgru + bias_g
        kGemm<<<dim3(gx, 2), 256, 0, stream>>>(mih, Wgru, bias_g, g, 256, 0);
        // GRU update -> mih[:, 64:]
        kCe<<<(NN * 16 + 255) / 256, 256, 0, stream>>>(g, mih);
    }
    kD<<<NN / 4, 128, 0, stream>>>(s_buf, mih, Wout, bout, ck, cb, out);
}

// Round 5
// 1492.640 us; speedup vs baseline: 1.9394x; 1.2138x over previous
//
#include <hip/hip_runtime.h>

#define TT 8
#define NN 50000
#define DD 128
#define HH 128
#define MM 64
#define EE 800000
#define NBLK 196  // ceil(NN/256)

typedef __attribute__((ext_vector_type(8))) short short8v;   // 8 bf16 = 4 VGPR
typedef __attribute__((ext_vector_type(4))) float f32x4;

__device__ __forceinline__ short bf16rn(float v) {
    unsigned u = __builtin_bit_cast(unsigned, v);
    unsigned r = (u + 0x7fffu + ((u >> 16) & 1u)) >> 16;
    return (short)r;
}
__device__ __forceinline__ float bf16tof(short h) {
    unsigned u = ((unsigned)(unsigned short)h) << 16;
    return __builtin_bit_cast(float, u);
}
__device__ __forceinline__ void bsplit(float v, short& h, short& l) {
    h = bf16rn(v);
    l = bf16rn(v - bf16tof(h));
}
__device__ __forceinline__ f32x4 mfma16(short8v a, short8v b, f32x4 c) {
    return __builtin_amdgcn_mfma_f32_16x16x32_bf16(a, b, c, 0, 0, 0);
}

// ---------------- edge conversion + degree histogram ----------------------
__global__ __launch_bounds__(256) void kConvEdges(const int* __restrict__ eraw,
                                                  int* __restrict__ src,
                                                  int* __restrict__ tgt,
                                                  int* __restrict__ deg) {
    bool is64 = true;
#pragma unroll
    for (int i = 0; i < 8; ++i)
        if (eraw[2 * i + 1] != 0) is64 = false;
    int i = blockIdx.x * blockDim.x + threadIdx.x;
    if (i < EE) {
        int s, t;
        if (is64) {
            const long long* e64 = (const long long*)eraw;
            s = (int)e64[i];
            t = (int)e64[EE + i];
        } else {
            s = eraw[i];
            t = eraw[EE + i];
        }
        s = min(max(s, 0), NN - 1);
        t = min(max(t, 0), NN - 1);
        src[i] = s;
        tgt[i] = t;
        atomicAdd(&deg[t], 1);
    }
}

// ---------------- hierarchical exclusive scan of deg -> rowptr ------------
__global__ __launch_bounds__(256) void kScanA(const int* __restrict__ deg,
                                              int* __restrict__ itmp,
                                              int* __restrict__ bsum) {
    __shared__ int sm[256];
    int gid = blockIdx.x * 256 + threadIdx.x;
    int v = (gid < NN) ? deg[gid] : 0;
    sm[threadIdx.x] = v;
    __syncthreads();
    for (int off = 1; off < 256; off <<= 1) {
        int add = (threadIdx.x >= off) ? sm[threadIdx.x - off] : 0;
        __syncthreads();
        sm[threadIdx.x] += add;
        __syncthreads();
    }
    itmp[gid] = sm[threadIdx.x];
    if (threadIdx.x == 255) bsum[blockIdx.x] = sm[255];
}

__global__ __launch_bounds__(256) void kScanB(const int* __restrict__ bsum,
                                              int* __restrict__ boffs) {
    __shared__ int sm[256];
    int v = (threadIdx.x < NBLK) ? bsum[threadIdx.x] : 0;
    sm[threadIdx.x] = v;
    __syncthreads();
    for (int off = 1; off < 256; off <<= 1) {
        int add = (threadIdx.x >= off) ? sm[threadIdx.x - off] : 0;
        __syncthreads();
        sm[threadIdx.x] += add;
        __syncthreads();
    }
    if (threadIdx.x < NBLK)
        boffs[threadIdx.x] = (threadIdx.x == 0) ? 0 : sm[threadIdx.x - 1];
}

__global__ __launch_bounds__(256) void kScanC(const int* __restrict__ itmp,
                                              const int* __restrict__ boffs,
                                              int* __restrict__ rowptr) {
    int gid = blockIdx.x * 256 + threadIdx.x;
    if (gid < NN) rowptr[gid + 1] = itmp[gid] + boffs[blockIdx.x];
    if (gid == 0) rowptr[0] = 0;
}

// ---------------- CSR fill -------------------------------------------------
__global__ __launch_bounds__(256) void kFill(const int* __restrict__ src,
                                             const int* __restrict__ tgt,
                                             const int* __restrict__ rowptr,
                                             int* __restrict__ cursor,
                                             int* __restrict__ csr_src) {
    int e = blockIdx.x * blockDim.x + threadIdx.x;
    if (e < EE) {
        int t = tgt[e];
        int p = atomicAdd(&cursor[t], 1);
        csr_src[rowptr[t] + p] = src[e];
    }
}

// ---------------- weight repack into fragment-major bf16 hi/lo packs ------
// Pack layout (shorts): [((ntg*4 + kt)*2 + hl)*512 + lane*8 + e]
// element = B[k = kt*32 + (lane>>4)*8 + e][col = ntg*16 + (lane&15)]
__global__ __launch_bounds__(256) void kPrep(const float* __restrict__ Wsp,
                                             const float* __restrict__ Wmp,
                                             const float* __restrict__ bmp,
                                             const float* __restrict__ Wi,
                                             const float* __restrict__ bi,
                                             const float* __restrict__ Wh,
                                             const float* __restrict__ bhn,
                                             short* __restrict__ Bp1,
                                             short* __restrict__ Bp2,
                                             short* __restrict__ Bp3,
                                             float* __restrict__ bias_aq,
                                             float* __restrict__ bias_g) {
    const int gid = blockIdx.x * 256 + threadIdx.x;
    const int gstride = gridDim.x * 256;

    // Bp1: Wsp [128][128], 8 ntiles
    for (int i = gid; i < 8 * 4 * 512; i += gstride) {
        int e = i & 7, lanei = (i >> 3) & 63, kt = (i >> 9) & 3, nt = i >> 11;
        int k = kt * 32 + (lanei >> 4) * 8 + e;
        int col = nt * 16 + (lanei & 15);
        float v = Wsp[k * 128 + col];
        short h, l;
        bsplit(v, h, l);
        Bp1[((nt * 4 + kt) * 2 + 0) * 512 + lanei * 8 + e] = h;
        Bp1[((nt * 4 + kt) * 2 + 1) * 512 + lanei * 8 + e] = l;
    }
    // Bp2: B2 [128][128] built from Wmp; cols<64: Wmp[k][c]; cols>=64: Wmp[128+k][c-64]
    for (int i = gid; i < 8 * 4 * 512; i += gstride) {
        int e = i & 7, lanei = (i >> 3) & 63, kt = (i >> 9) & 3, nt = i >> 11;
        int k = kt * 32 + (lanei >> 4) * 8 + e;
        int col = nt * 16 + (lanei & 15);
        float v = (col < 64) ? Wmp[k * 64 + col] : Wmp[(128 + k) * 64 + (col - 64)];
        short h, l;
        bsplit(v, h, l);
        Bp2[((nt * 4 + kt) * 2 + 0) * 512 + lanei * 8 + e] = h;
        Bp2[((nt * 4 + kt) * 2 + 1) * 512 + lanei * 8 + e] = l;
    }
    // Bp3: Wgru [128][256] logical, 16 ntiles; A = [mi | h]
    for (int i = gid; i < 16 * 4 * 512; i += gstride) {
        int e = i & 7, lanei = (i >> 3) & 63, kt = (i >> 9) & 3, nt = i >> 11;
        int k = kt * 32 + (lanei >> 4) * 8 + e;
        int col = nt * 16 + (lanei & 15);
        float v;
        if (k < 64) {
            v = (col < 192) ? Wi[k * 192 + col] : 0.f;
        } else {
            int kk = k - 64;
            if (col < 128)      v = Wh[kk * 192 + col];
            else if (col < 192) v = 0.f;
            else                v = Wh[kk * 192 + (col - 64)];
        }
        short h, l;
        bsplit(v, h, l);
        Bp3[((nt * 4 + kt) * 2 + 0) * 512 + lanei * 8 + e] = h;
        Bp3[((nt * 4 + kt) * 2 + 1) * 512 + lanei * 8 + e] = l;
    }
    if (gid < 128) bias_aq[gid] = (gid < 64) ? bmp[gid] : 0.f;
    if (gid < 256) bias_g[gid] = (gid < 192) ? bi[gid] : bhn[gid - 192];
}

// ---------------- split-bf16 MFMA GEMM: C[N x 128] = A[N x 128] @ B -------
// 4 waves; wave w: rows 64*bx + 32*(w&1), cols 64*(w>>1). No LDS.
__global__ __launch_bounds__(256) void kGemm12(const float* __restrict__ A,
                                               const short* __restrict__ Bp,
                                               const float* __restrict__ bias,
                                               float* __restrict__ C,
                                               int relu) {
    const int tid = threadIdx.x, lane = tid & 63, w = tid >> 6;
    const int rowBase = blockIdx.x * 64 + (w & 1) * 32;
    const int colBase = (w >> 1) * 64;

    short8v ah[2][4], al[2][4];
#pragma unroll
    for (int mt = 0; mt < 2; ++mt) {
        int row = min(rowBase + mt * 16 + (lane & 15), NN - 1);
        const float* ar = A + (size_t)row * 128 + (lane >> 4) * 8;
#pragma unroll
        for (int kt = 0; kt < 4; ++kt) {
            float4 x0 = *(const float4*)(ar + kt * 32);
            float4 x1 = *(const float4*)(ar + kt * 32 + 4);
            float xs[8] = {x0.x, x0.y, x0.z, x0.w, x1.x, x1.y, x1.z, x1.w};
#pragma unroll
            for (int e = 0; e < 8; ++e) {
                short h, l;
                bsplit(xs[e], h, l);
                ah[mt][kt][e] = h;
                al[mt][kt][e] = l;
            }
        }
    }

    f32x4 acc[2][4];
#pragma unroll
    for (int mt = 0; mt < 2; ++mt)
#pragma unroll
        for (int nt = 0; nt < 4; ++nt) acc[mt][nt] = (f32x4)0.f;

#pragma unroll
    for (int nt = 0; nt < 4; ++nt) {
        const int ntg = (colBase >> 4) + nt;
#pragma unroll
        for (int kt = 0; kt < 4; ++kt) {
            short8v bh = *(const short8v*)&Bp[((ntg * 4 + kt) * 2 + 0) * 512 + lane * 8];
            short8v bl = *(const short8v*)&Bp[((ntg * 4 + kt) * 2 + 1) * 512 + lane * 8];
#pragma unroll
            for (int mt = 0; mt < 2; ++mt) {
                acc[mt][nt] = mfma16(ah[mt][kt], bh, acc[mt][nt]);
                acc[mt][nt] = mfma16(ah[mt][kt], bl, acc[mt][nt]);
                acc[mt][nt] = mfma16(al[mt][kt], bh, acc[mt][nt]);
            }
        }
    }

#pragma unroll
    for (int mt = 0; mt < 2; ++mt)
#pragma unroll
        for (int nt = 0; nt < 4; ++nt) {
            int col = colBase + nt * 16 + (lane & 15);
            float bb = bias[col];
            int r0 = rowBase + mt * 16 + (lane >> 4) * 4;
#pragma unroll
            for (int r = 0; r < 4; ++r) {
                int row = r0 + r;
                if (row < NN) {
                    float v = acc[mt][nt][r] + bb;
                    if (relu) v = fmaxf(v, 0.f);
                    C[(size_t)row * 128 + col] = v;
                }
            }
        }
}

// ---------------- GRU GEMM + epilogue: g = mih@Wgru+bias_g; h' in place ---
// block: 32 rows x 256 cols; wave w covers cols 64w (2 mtiles x 4 ntiles).
__global__ __launch_bounds__(256) void kGemm3(float* __restrict__ mih,
                                              const short* __restrict__ Bp,
                                              const float* __restrict__ bias_g) {
    __shared__ float gT[256][36];  // [col][row], pad 36 (16B-aligned, bank-spread)
    const int tid = threadIdx.x, lane = tid & 63, w = tid >> 6;
    const int rowBase = blockIdx.x * 32;
    const int colBase = w * 64;

    short8v ah[2][4], al[2][4];
#pragma unroll
    for (int mt = 0; mt < 2; ++mt) {
        int row = min(rowBase + mt * 16 + (lane & 15), NN - 1);
        const float* ar = mih + (size_t)row * 128 + (lane >> 4) * 8;
#pragma unroll
        for (int kt = 0; kt < 4; ++kt) {
            float4 x0 = *(const float4*)(ar + kt * 32);
            float4 x1 = *(const float4*)(ar + kt * 32 + 4);
            float xs[8] = {x0.x, x0.y, x0.z, x0.w, x1.x, x1.y, x1.z, x1.w};
#pragma unroll
            for (int e = 0; e < 8; ++e) {
                short h, l;
                bsplit(xs[e], h, l);
                ah[mt][kt][e] = h;
                al[mt][kt][e] = l;
            }
        }
    }

    f32x4 acc[2][4];
#pragma unroll
    for (int mt = 0; mt < 2; ++mt)
#pragma unroll
        for (int nt = 0; nt < 4; ++nt) acc[mt][nt] = (f32x4)0.f;

#pragma unroll
    for (int nt = 0; nt < 4; ++nt) {
        const int ntg = (colBase >> 4) + nt;
#pragma unroll
        for (int kt = 0; kt < 4; ++kt) {
            short8v bh = *(const short8v*)&Bp[((ntg * 4 + kt) * 2 + 0) * 512 + lane * 8];
            short8v bl = *(const short8v*)&Bp[((ntg * 4 + kt) * 2 + 1) * 512 + lane * 8];
#pragma unroll
            for (int mt = 0; mt < 2; ++mt) {
                acc[mt][nt] = mfma16(ah[mt][kt], bh, acc[mt][nt]);
                acc[mt][nt] = mfma16(ah[mt][kt], bl, acc[mt][nt]);
                acc[mt][nt] = mfma16(al[mt][kt], bh, acc[mt][nt]);
            }
        }
    }

    // stage g (with bias) into LDS, transposed [col][row]
#pragma unroll
    for (int mt = 0; mt < 2; ++mt)
#pragma unroll
        for (int nt = 0; nt < 4; ++nt) {
            int col = colBase + nt * 16 + (lane & 15);
            int r0 = mt * 16 + (lane >> 4) * 4;
            f32x4 v = acc[mt][nt] + bias_g[col];
            *(f32x4*)&gT[col][r0] = v;
        }
    __syncthreads();

    // GRU epilogue: 32 rows x 64 cols = 2048 outputs, 8 per thread
#pragma unroll
    for (int i = 0; i < 8; ++i) {
        int idx = i * 256 + tid;
        int row = idx & 31, c = idx >> 5;
        int node = rowBase + row;
        if (node >= NN) continue;
        float xr = gT[c][row];
        float xz = gT[c + 64][row];
        float xni = gT[c + 128][row];
        float xnh = gT[c + 192][row];
        float* hp = &mih[(size_t)node * 128 + 64 + c];
        float hv = *hp;
        float r = 1.f / (1.f + __expf(-xr));
        float z = 1.f / (1.f + __expf(-xz));
        float xn = xni + r * xnh;
        float e2 = __expf(2.f * xn);
        float nn = 1.f - 2.f / (e2 + 1.f);  // tanh
        *hp = (1.f - z) * nn + z * hv;
    }
}

// ---------------- gather: mih[:, :64] = a + sum q[src] --------------------
__global__ __launch_bounds__(256) void kGather(const float* __restrict__ aq,
                                               const int* __restrict__ rowptr,
                                               const int* __restrict__ csr_src,
                                               float* __restrict__ mih) {
    const int lane = threadIdx.x & 63;
    const int w = (blockIdx.x * blockDim.x + threadIdx.x) >> 6;
    if (w >= NN) return;
    const int beg = rowptr[w];
    const int end = rowptr[w + 1];
    float acc0 = 0.f, acc1 = 0.f;
    int i = beg;
    for (; i + 1 < end; i += 2) {
        int s0 = csr_src[i];
        int s1 = csr_src[i + 1];
        acc0 += aq[(size_t)s0 * 128 + 64 + lane];
        acc1 += aq[(size_t)s1 * 128 + 64 + lane];
    }
    if (i < end) acc0 += aq[(size_t)csr_src[i] * 128 + 64 + lane];
    mih[(size_t)w * 128 + lane] = acc0 + acc1 + aq[(size_t)w * 128 + lane];
}

// ---------------- kernel D: out = [s,h]@Wout+bout; conv over feature axis --
__global__ __launch_bounds__(128) void kD(const float* __restrict__ s_buf,
                                          const float* __restrict__ mih,
                                          const float* __restrict__ Wout,
                                          const float* __restrict__ bout,
                                          const float* __restrict__ convk,
                                          const float* __restrict__ convb,
                                          float* __restrict__ out) {
    __shared__ float ss[4][HH];
    __shared__ float hs[4][MM];
    __shared__ float os[4][HH];
    const int j = threadIdx.x;
    const int base = blockIdx.x * 4;

#pragma unroll
    for (int n = 0; n < 4; ++n)
        ss[n][j] = s_buf[(size_t)(base + n) * HH + j];
    for (int idx = j; idx < 4 * MM; idx += 128) {
        int n = idx >> 6, c = idx & 63;
        hs[n][c] = mih[(size_t)(base + n) * 128 + 64 + c];
    }
    __syncthreads();

    float acc[4];
    const float bj = bout[j];
#pragma unroll
    for (int n = 0; n < 4; ++n) acc[n] = bj;
#pragma unroll 4
    for (int k = 0; k < HH; ++k) {
        float w = Wout[k * HH + j];
#pragma unroll
        for (int n = 0; n < 4; ++n) acc[n] = fmaf(ss[n][k], w, acc[n]);
    }
#pragma unroll 4
    for (int k = 0; k < MM; ++k) {
        float w = Wout[(HH + k) * HH + j];
#pragma unroll
        for (int n = 0; n < 4; ++n) acc[n] = fmaf(hs[n][k], w, acc[n]);
    }
#pragma unroll
    for (int n = 0; n < 4; ++n) os[n][j] = acc[n];
    __syncthreads();

    float ck[10];
#pragma unroll
    for (int i = 0; i < 10; ++i) ck[i] = convk[i * HH];
    const float cb = convb[0];
#pragma unroll
    for (int n = 0; n < 4; ++n) {
        float y = cb;
#pragma unroll
        for (int i = 0; i < 10; ++i) {
            int p = j - 4 + i;
            float xv = (p >= 0 && p < HH) ? os[n][p] : 0.f;
            y = fmaf(xv, ck[i], y);
        }
        out[(size_t)(base + n) * HH + j] = y;
    }
    for (int idx = j; idx < 4 * MM; idx += 128) {
        int n = idx >> 6, c = idx & 63;
        out[(size_t)NN * HH + (size_t)(base + n) * MM + c] = hs[n][c];
    }
}

extern "C" void kernel_launch(void* const* d_in, const int* in_sizes, int n_in,
                              void* d_out, int out_size, void* d_ws, size_t ws_size,
                              hipStream_t stream) {
    const float* X    = (const float*)d_in[0];
    const int*   eraw = (const int*)d_in[1];
    const float* Wsp  = (const float*)d_in[2];
    const float* bsp  = (const float*)d_in[3];
    const float* Wmp  = (const float*)d_in[4];
    const float* bmp  = (const float*)d_in[5];
    const float* Wi   = (const float*)d_in[6];
    const float* bi   = (const float*)d_in[7];
    const float* Wh   = (const float*)d_in[8];
    const float* bhn  = (const float*)d_in[9];
    const float* Wout = (const float*)d_in[10];
    const float* bout = (const float*)d_in[11];
    const float* ck   = (const float*)d_in[12];
    const float* cb   = (const float*)d_in[13];
    float* out = (float*)d_out;

    float* ws = (float*)d_ws;
    float* s_buf  = ws;                          // N*128
    float* aq     = s_buf + (size_t)NN * 128;    // N*128
    float* mih    = aq + (size_t)NN * 128;       // N*128  ([a+msg | h])
    float* bias_aq= mih + (size_t)NN * 128;      // 128
    float* bias_g = bias_aq + 128;               // 256
    short* Bp1    = (short*)(bias_g + 256);      // 32768 shorts
    short* Bp2    = Bp1 + 8 * 4 * 2 * 512;       // 32768
    short* Bp3    = Bp2 + 8 * 4 * 2 * 512;       // 65536
    int*   src     = (int*)(Bp3 + 16 * 4 * 2 * 512);
    int*   tgt     = src + EE;
    int*   csr_src = tgt + EE;
    int*   deg     = csr_src + EE;               // N
    int*   rowptr  = deg + NN;                   // N+1
    int*   cursor  = rowptr + NN + 1;            // N
    int*   itmp    = cursor + NN;                // NBLK*256
    int*   bsum    = itmp + NBLK * 256;          // 256
    int*   boffs   = bsum + 256;                 // 256

    hipMemsetAsync(mih, 0, (size_t)NN * 128 * sizeof(float), stream);  // h0 = 0
    hipMemsetAsync(deg, 0, NN * sizeof(int), stream);
    hipMemsetAsync(cursor, 0, NN * sizeof(int), stream);

    kConvEdges<<<(EE + 255) / 256, 256, 0, stream>>>(eraw, src, tgt, deg);
    kScanA<<<NBLK, 256, 0, stream>>>(deg, itmp, bsum);
    kScanB<<<1, 256, 0, stream>>>(bsum, boffs);
    kScanC<<<NBLK, 256, 0, stream>>>(itmp, boffs, rowptr);
    kFill<<<(EE + 255) / 256, 256, 0, stream>>>(src, tgt, rowptr, cursor, csr_src);
    kPrep<<<64, 256, 0, stream>>>(Wsp, Wmp, bmp, Wi, bi, Wh, bhn,
                                  Bp1, Bp2, Bp3, bias_aq, bias_g);

    const int gx12 = (NN + 63) / 64;   // 782
    const int gx3  = (NN + 31) / 32;   // 1563
    for (int t = 0; t < TT; ++t) {
        // s = relu(X_t @ Wsp + bsp)
        kGemm12<<<gx12, 256, 0, stream>>>(X + (size_t)t * NN * DD, Bp1, bsp, s_buf, 1);
        // aq = s @ B2 + bias_aq
        kGemm12<<<gx12, 256, 0, stream>>>(s_buf, Bp2, bias_aq, aq, 0);
        // mih[:, :64] = a + gather(q)
        kGather<<<(NN * 64 + 255) / 256, 256, 0, stream>>>(aq, rowptr, csr_src, mih);
        // g = mih @ Wgru + bias_g; GRU epilogue -> mih[:, 64:]
        kGemm3<<<gx3, 256, 0, stream>>>(mih, Bp3, bias_g);
    }
    kD<<<NN / 4, 128, 0, stream>>>(s_buf, mih, Wout, bout, ck, cb, out);
}

// Round 7
// 1280.795 us; speedup vs baseline: 2.2602x; 1.1654x over previous
//
#include <hip/hip_runtime.h>

#define TT 8
#define NN 50000
#define DD 128
#define HH 128
#define MM 64
#define EE 800000
#define NBLK 196  // ceil(NN/256)

typedef __attribute__((ext_vector_type(8))) short short8v;   // 8 bf16 = 4 VGPR
typedef __attribute__((ext_vector_type(4))) float f32x4;

__device__ __forceinline__ unsigned bf16rn_bits(float v) {
    unsigned u = __builtin_bit_cast(unsigned, v);
    return (u + 0x7fffu + ((u >> 16) & 1u)) >> 16;
}
__device__ __forceinline__ short bf16rn(float v) { return (short)bf16rn_bits(v); }
__device__ __forceinline__ float bf16tof_bits(unsigned hb16) {
    return __builtin_bit_cast(float, hb16 << 16);
}
__device__ __forceinline__ void bsplit(float v, short& h, short& l) {
    // rounded-hi split (used where we split fp32 loaded from global)
    h = bf16rn(v);
    l = bf16rn(v - bf16tof_bits((unsigned)(unsigned short)h));
}
// packed split: hi = truncated bf16 (exact bits), lo = rounded remainder
__device__ __forceinline__ unsigned packsplit(float v) {
    unsigned u = __builtin_bit_cast(unsigned, v);
    unsigned hb = u & 0xFFFF0000u;
    float lo = v - __builtin_bit_cast(float, hb);
    return hb | (bf16rn_bits(lo) & 0xFFFFu);
}
__device__ __forceinline__ float unpack_val(unsigned p) {
    float hi = __builtin_bit_cast(float, p & 0xFFFF0000u);
    float lo = __builtin_bit_cast(float, p << 16);
    return hi + lo;
}
__device__ __forceinline__ f32x4 mfma16(short8v a, short8v b, f32x4 c) {
    return __builtin_amdgcn_mfma_f32_16x16x32_bf16(a, b, c, 0, 0, 0);
}

// ---------------- edge conversion + degree histogram ----------------------
__global__ __launch_bounds__(256) void kConvEdges(const int* __restrict__ eraw,
                                                  int* __restrict__ src,
                                                  int* __restrict__ tgt,
                                                  int* __restrict__ deg) {
    bool is64 = true;
#pragma unroll
    for (int i = 0; i < 8; ++i)
        if (eraw[2 * i + 1] != 0) is64 = false;
    int i = blockIdx.x * blockDim.x + threadIdx.x;
    if (i < EE) {
        int s, t;
        if (is64) {
            const long long* e64 = (const long long*)eraw;
            s = (int)e64[i];
            t = (int)e64[EE + i];
        } else {
            s = eraw[i];
            t = eraw[EE + i];
        }
        s = min(max(s, 0), NN - 1);
        t = min(max(t, 0), NN - 1);
        src[i] = s;
        tgt[i] = t;
        atomicAdd(&deg[t], 1);
    }
}

// ---------------- hierarchical exclusive scan of deg -> rowptr ------------
__global__ __launch_bounds__(256) void kScanA(const int* __restrict__ deg,
                                              int* __restrict__ itmp,
                                              int* __restrict__ bsum) {
    __shared__ int sm[256];
    int gid = blockIdx.x * 256 + threadIdx.x;
    int v = (gid < NN) ? deg[gid] : 0;
    sm[threadIdx.x] = v;
    __syncthreads();
    for (int off = 1; off < 256; off <<= 1) {
        int add = (threadIdx.x >= off) ? sm[threadIdx.x - off] : 0;
        __syncthreads();
        sm[threadIdx.x] += add;
        __syncthreads();
    }
    itmp[gid] = sm[threadIdx.x];
    if (threadIdx.x == 255) bsum[blockIdx.x] = sm[255];
}

__global__ __launch_bounds__(256) void kScanB(const int* __restrict__ bsum,
                                              int* __restrict__ boffs) {
    __shared__ int sm[256];
    int v = (threadIdx.x < NBLK) ? bsum[threadIdx.x] : 0;
    sm[threadIdx.x] = v;
    __syncthreads();
    for (int off = 1; off < 256; off <<= 1) {
        int add = (threadIdx.x >= off) ? sm[threadIdx.x - off] : 0;
        __syncthreads();
        sm[threadIdx.x] += add;
        __syncthreads();
    }
    if (threadIdx.x < NBLK)
        boffs[threadIdx.x] = (threadIdx.x == 0) ? 0 : sm[threadIdx.x - 1];
}

__global__ __launch_bounds__(256) void kScanC(const int* __restrict__ itmp,
                                              const int* __restrict__ boffs,
                                              int* __restrict__ rowptr) {
    int gid = blockIdx.x * 256 + threadIdx.x;
    if (gid < NN) rowptr[gid + 1] = itmp[gid] + boffs[blockIdx.x];
    if (gid == 0) rowptr[0] = 0;
}

// ---------------- CSR fill -------------------------------------------------
__global__ __launch_bounds__(256) void kFill(const int* __restrict__ src,
                                             const int* __restrict__ tgt,
                                             const int* __restrict__ rowptr,
                                             int* __restrict__ cursor,
                                             int* __restrict__ csr_src) {
    int e = blockIdx.x * blockDim.x + threadIdx.x;
    if (e < EE) {
        int t = tgt[e];
        int p = atomicAdd(&cursor[t], 1);
        csr_src[rowptr[t] + p] = src[e];
    }
}

// ---------------- weight repack into fragment-major bf16 hi/lo packs ------
// Pack layout (shorts): [((ntg*4 + kt)*2 + hl)*512 + lane*8 + e]
// element = B[k = kt*32 + (lane>>4)*8 + e][col = ntg*16 + (lane&15)]
__global__ __launch_bounds__(256) void kPrep(const float* __restrict__ Wsp,
                                             const float* __restrict__ Wmp,
                                             const float* __restrict__ Wi,
                                             const float* __restrict__ bi,
                                             const float* __restrict__ Wh,
                                             const float* __restrict__ bhn,
                                             short* __restrict__ Bp1,
                                             short* __restrict__ Bp2,
                                             short* __restrict__ Bp3,
                                             float* __restrict__ bias_g) {
    const int gid = blockIdx.x * 256 + threadIdx.x;
    const int gstride = gridDim.x * 256;

    // Bp1: Wsp [128][128], 8 ntiles
    for (int i = gid; i < 8 * 4 * 512; i += gstride) {
        int e = i & 7, lanei = (i >> 3) & 63, kt = (i >> 9) & 3, nt = i >> 11;
        int k = kt * 32 + (lanei >> 4) * 8 + e;
        int col = nt * 16 + (lanei & 15);
        float v = Wsp[k * 128 + col];
        short h, l;
        bsplit(v, h, l);
        Bp1[((nt * 4 + kt) * 2 + 0) * 512 + lanei * 8 + e] = h;
        Bp1[((nt * 4 + kt) * 2 + 1) * 512 + lanei * 8 + e] = l;
    }
    // Bp2: B2 [128][128] from Wmp; cols<64: Wmp[k][c] (a); cols>=64: Wmp[128+k][c-64] (q)
    for (int i = gid; i < 8 * 4 * 512; i += gstride) {
        int e = i & 7, lanei = (i >> 3) & 63, kt = (i >> 9) & 3, nt = i >> 11;
        int k = kt * 32 + (lanei >> 4) * 8 + e;
        int col = nt * 16 + (lanei & 15);
        float v = (col < 64) ? Wmp[k * 64 + col] : Wmp[(128 + k) * 64 + (col - 64)];
        short h, l;
        bsplit(v, h, l);
        Bp2[((nt * 4 + kt) * 2 + 0) * 512 + lanei * 8 + e] = h;
        Bp2[((nt * 4 + kt) * 2 + 1) * 512 + lanei * 8 + e] = l;
    }
    // Bp3: Wgru [128][256] logical; A = [mi | h]
    for (int i = gid; i < 16 * 4 * 512; i += gstride) {
        int e = i & 7, lanei = (i >> 3) & 63, kt = (i >> 9) & 3, nt = i >> 11;
        int k = kt * 32 + (lanei >> 4) * 8 + e;
        int col = nt * 16 + (lanei & 15);
        float v;
        if (k < 64) {
            v = (col < 192) ? Wi[k * 192 + col] : 0.f;
        } else {
            int kk = k - 64;
            if (col < 128)      v = Wh[kk * 192 + col];
            else if (col < 192) v = 0.f;
            else                v = Wh[kk * 192 + (col - 64)];
        }
        short h, l;
        bsplit(v, h, l);
        Bp3[((nt * 4 + kt) * 2 + 0) * 512 + lanei * 8 + e] = h;
        Bp3[((nt * 4 + kt) * 2 + 1) * 512 + lanei * 8 + e] = l;
    }
    if (gid < 256) bias_g[gid] = (gid < 192) ? bi[gid] : bhn[gid - 192];
}

// ---------------- kFF: fused s = relu(X@Wsp+bsp); a,q = s@B2 for ALL T*N rows
// 64 rows/block over T*N = 400000 rows (6250 blocks exactly).
// wave w: rows 32*(w&1)..+32, cols 64*(w>>1)..+64. s staged packed in LDS.
__global__ __launch_bounds__(256) void kFF(const float* __restrict__ X,
                                           const short* __restrict__ Bp1,
                                           const float* __restrict__ bsp,
                                           const short* __restrict__ Bp2,
                                           const float* __restrict__ bmp,
                                           float* __restrict__ a_all,
                                           unsigned short* __restrict__ qb_all,
                                           float* __restrict__ s_buf) {
    __shared__ unsigned sPk[64][132];  // packed split s, +4 pad
    const int tid = threadIdx.x, lane = tid & 63, w = tid >> 6;
    const size_t rowBlk = (size_t)blockIdx.x * 64;
    const int rhalf = (w & 1) * 32;
    const int colBase = (w >> 1) * 64;

    short8v ah[2][4], al[2][4];
    // ---- phase 1: load X fragments, split ----
#pragma unroll
    for (int mt = 0; mt < 2; ++mt) {
        size_t row = rowBlk + rhalf + mt * 16 + (lane & 15);
        const float* ar = X + row * 128 + (lane >> 4) * 8;
#pragma unroll
        for (int kt = 0; kt < 4; ++kt) {
            float4 x0 = *(const float4*)(ar + kt * 32);
            float4 x1 = *(const float4*)(ar + kt * 32 + 4);
            float xs[8] = {x0.x, x0.y, x0.z, x0.w, x1.x, x1.y, x1.z, x1.w};
#pragma unroll
            for (int e = 0; e < 8; ++e) {
                short h, l;
                bsplit(xs[e], h, l);
                ah[mt][kt][e] = h;
                al[mt][kt][e] = l;
            }
        }
    }

    f32x4 acc[2][4];
#pragma unroll
    for (int mt = 0; mt < 2; ++mt)
#pragma unroll
        for (int nt = 0; nt < 4; ++nt) acc[mt][nt] = (f32x4)0.f;

#pragma unroll
    for (int nt = 0; nt < 4; ++nt) {
        const int ntg = (colBase >> 4) + nt;
#pragma unroll
        for (int kt = 0; kt < 4; ++kt) {
            short8v bh = *(const short8v*)&Bp1[((ntg * 4 + kt) * 2 + 0) * 512 + lane * 8];
            short8v bl = *(const short8v*)&Bp1[((ntg * 4 + kt) * 2 + 1) * 512 + lane * 8];
#pragma unroll
            for (int mt = 0; mt < 2; ++mt) {
                acc[mt][nt] = mfma16(ah[mt][kt], bh, acc[mt][nt]);
                acc[mt][nt] = mfma16(ah[mt][kt], bl, acc[mt][nt]);
                acc[mt][nt] = mfma16(al[mt][kt], bh, acc[mt][nt]);
            }
        }
    }

    // ---- s epilogue: bias, relu, pack to LDS; write s_buf for t == TT-1 ----
#pragma unroll
    for (int mt = 0; mt < 2; ++mt)
#pragma unroll
        for (int nt = 0; nt < 4; ++nt) {
            int col = colBase + nt * 16 + (lane & 15);
            float b = bsp[col];
            int lr0 = rhalf + mt * 16 + (lane >> 4) * 4;
#pragma unroll
            for (int r = 0; r < 4; ++r) {
                float sv = fmaxf(acc[mt][nt][r] + b, 0.f);
                sPk[lr0 + r][col] = packsplit(sv);
                size_t row = rowBlk + lr0 + r;
                if (row >= (size_t)(TT - 1) * NN)
                    s_buf[(row - (size_t)(TT - 1) * NN) * 128 + col] = sv;
            }
        }
    __syncthreads();

    // ---- phase 2: reload s fragments from LDS (cheap unpack) ----
#pragma unroll
    for (int mt = 0; mt < 2; ++mt) {
        int lr = rhalf + mt * 16 + (lane & 15);
#pragma unroll
        for (int kt = 0; kt < 4; ++kt) {
            int k0 = kt * 32 + (lane >> 4) * 8;
            uint4 p0 = *(const uint4*)&sPk[lr][k0];
            uint4 p1 = *(const uint4*)&sPk[lr][k0 + 4];
            unsigned ps[8] = {p0.x, p0.y, p0.z, p0.w, p1.x, p1.y, p1.z, p1.w};
#pragma unroll
            for (int e = 0; e < 8; ++e) {
                ah[mt][kt][e] = (short)(ps[e] >> 16);
                al[mt][kt][e] = (short)(ps[e] & 0xFFFFu);
            }
        }
    }

#pragma unroll
    for (int mt = 0; mt < 2; ++mt)
#pragma unroll
        for (int nt = 0; nt < 4; ++nt) acc[mt][nt] = (f32x4)0.f;

#pragma unroll
    for (int nt = 0; nt < 4; ++nt) {
        const int ntg = (colBase >> 4) + nt;
#pragma unroll
        for (int kt = 0; kt < 4; ++kt) {
            short8v bh = *(const short8v*)&Bp2[((ntg * 4 + kt) * 2 + 0) * 512 + lane * 8];
            short8v bl = *(const short8v*)&Bp2[((ntg * 4 + kt) * 2 + 1) * 512 + lane * 8];
#pragma unroll
            for (int mt = 0; mt < 2; ++mt) {
                acc[mt][nt] = mfma16(ah[mt][kt], bh, acc[mt][nt]);
                acc[mt][nt] = mfma16(ah[mt][kt], bl, acc[mt][nt]);
                acc[mt][nt] = mfma16(al[mt][kt], bh, acc[mt][nt]);
            }
        }
    }

    // ---- aq epilogue: cols<64 -> a fp32 (+bmp); cols>=64 -> q bf16 ----
#pragma unroll
    for (int mt = 0; mt < 2; ++mt)
#pragma unroll
        for (int nt = 0; nt < 4; ++nt) {
            int col = colBase + nt * 16 + (lane & 15);
            int lr0 = rhalf + mt * 16 + (lane >> 4) * 4;
            if (col < 64) {
                float b = bmp[col];
#pragma unroll
                for (int r = 0; r < 4; ++r) {
                    size_t row = rowBlk + lr0 + r;
                    a_all[row * 64 + col] = acc[mt][nt][r] + b;
                }
            } else {
#pragma unroll
                for (int r = 0; r < 4; ++r) {
                    size_t row = rowBlk + lr0 + r;
                    qb_all[row * 64 + (col - 64)] =
                        (unsigned short)bf16rn_bits(acc[mt][nt][r]);
                }
            }
        }
}

// ---------------- gather: mihp[:, :64] = packsplit(a + sum bf16 q[src]) ---
__global__ __launch_bounds__(256) void kGatherB(const float* __restrict__ a_t,
                                                const unsigned short* __restrict__ qb_t,
                                                const int* __restrict__ rowptr,
                                                const int* __restrict__ csr_src,
                                                unsigned* __restrict__ mihp) {
    const int lane = threadIdx.x & 63;
    const int w = (blockIdx.x * blockDim.x + threadIdx.x) >> 6;
    if (w >= NN) return;
    const int beg = rowptr[w];
    const int end = rowptr[w + 1];
    float acc0 = 0.f, acc1 = 0.f;
    int i = beg;
    for (; i + 1 < end; i += 2) {
        int s0 = csr_src[i];
        int s1 = csr_src[i + 1];
        acc0 += bf16tof_bits(qb_t[(size_t)s0 * 64 + lane]);
        acc1 += bf16tof_bits(qb_t[(size_t)s1 * 64 + lane]);
    }
    if (i < end) acc0 += bf16tof_bits(qb_t[(size_t)csr_src[i] * 64 + lane]);
    float mi = acc0 + acc1 + a_t[(size_t)w * 64 + lane];
    mihp[(size_t)w * 128 + lane] = packsplit(mi);
}

// ---------------- GRU GEMM + epilogue on packed mih -----------------------
// block: 32 rows x 256 cols; wave w covers cols 64w.
__global__ __launch_bounds__(256) void kGemm3(unsigned* __restrict__ mihp,
                                              const short* __restrict__ Bp3,
                                              const float* __restrict__ bias_g) {
    __shared__ float gT[256][36];
    const int tid = threadIdx.x, lane = tid & 63, w = tid >> 6;
    const int rowBase = blockIdx.x * 32;
    const int colBase = w * 64;

    short8v ah[2][4], al[2][4];
#pragma unroll
    for (int mt = 0; mt < 2; ++mt) {
        int row = min(rowBase + mt * 16 + (lane & 15), NN - 1);
        const unsigned* ar = mihp + (size_t)row * 128 + (lane >> 4) * 8;
#pragma unroll
        for (int kt = 0; kt < 4; ++kt) {
            uint4 p0 = *(const uint4*)(ar + kt * 32);
            uint4 p1 = *(const uint4*)(ar + kt * 32 + 4);
            unsigned ps[8] = {p0.x, p0.y, p0.z, p0.w, p1.x, p1.y, p1.z, p1.w};
#pragma unroll
            for (int e = 0; e < 8; ++e) {
                ah[mt][kt][e] = (short)(ps[e] >> 16);
                al[mt][kt][e] = (short)(ps[e] & 0xFFFFu);
            }
        }
    }

    f32x4 acc[2][4];
#pragma unroll
    for (int mt = 0; mt < 2; ++mt)
#pragma unroll
        for (int nt = 0; nt < 4; ++nt) acc[mt][nt] = (f32x4)0.f;

#pragma unroll
    for (int nt = 0; nt < 4; ++nt) {
        const int ntg = (colBase >> 4) + nt;
#pragma unroll
        for (int kt = 0; kt < 4; ++kt) {
            short8v bh = *(const short8v*)&Bp3[((ntg * 4 + kt) * 2 + 0) * 512 + lane * 8];
            short8v bl = *(const short8v*)&Bp3[((ntg * 4 + kt) * 2 + 1) * 512 + lane * 8];
#pragma unroll
            for (int mt = 0; mt < 2; ++mt) {
                acc[mt][nt] = mfma16(ah[mt][kt], bh, acc[mt][nt]);
                acc[mt][nt] = mfma16(ah[mt][kt], bl, acc[mt][nt]);
                acc[mt][nt] = mfma16(al[mt][kt], bh, acc[mt][nt]);
            }
        }
    }

    // stage g (with bias) into LDS, transposed [col][row]
#pragma unroll
    for (int mt = 0; mt < 2; ++mt)
#pragma unroll
        for (int nt = 0; nt < 4; ++nt) {
            int col = colBase + nt * 16 + (lane & 15);
            int r0 = mt * 16 + (lane >> 4) * 4;
            f32x4 v = acc[mt][nt] + bias_g[col];
            *(f32x4*)&gT[col][r0] = v;
        }
    __syncthreads();

    // GRU epilogue: h_new packed back into mihp[:, 64:]
#pragma unroll
    for (int i = 0; i < 8; ++i) {
        int idx = i * 256 + tid;
        int row = idx & 31, c = idx >> 5;
        int node = rowBase + row;
        if (node >= NN) continue;
        float xr = gT[c][row];
        float xz = gT[c + 64][row];
        float xni = gT[c + 128][row];
        float xnh = gT[c + 192][row];
        unsigned* hp = &mihp[(size_t)node * 128 + 64 + c];
        float hv = unpack_val(*hp);
        float r = 1.f / (1.f + __expf(-xr));
        float z = 1.f / (1.f + __expf(-xz));
        float xn = xni + r * xnh;
        float e2 = __expf(2.f * xn);
        float nn = 1.f - 2.f / (e2 + 1.f);  // tanh
        *hp = packsplit((1.f - z) * nn + z * hv);
    }
}

// ---------------- kernel D: out = [s,h]@Wout+bout; conv over feature axis --
__global__ __launch_bounds__(128) void kD(const float* __restrict__ s_buf,
                                          const unsigned* __restrict__ mihp,
                                          const float* __restrict__ Wout,
                                          const float* __restrict__ bout,
                                          const float* __restrict__ convk,
                                          const float* __restrict__ convb,
                                          float* __restrict__ out) {
    __shared__ float ss[4][HH];
    __shared__ float hs[4][MM];
    __shared__ float os[4][HH];
    const int j = threadIdx.x;
    const int base = blockIdx.x * 4;

#pragma unroll
    for (int n = 0; n < 4; ++n)
        ss[n][j] = s_buf[(size_t)(base + n) * HH + j];
    for (int idx = j; idx < 4 * MM; idx += 128) {
        int n = idx >> 6, c = idx & 63;
        hs[n][c] = unpack_val(mihp[(size_t)(base + n) * 128 + 64 + c]);
    }
    __syncthreads();

    float acc[4];
    const float bj = bout[j];
#pragma unroll
    for (int n = 0; n < 4; ++n) acc[n] = bj;
#pragma unroll 4
    for (int k = 0; k < HH; ++k) {
        float w = Wout[k * HH + j];
#pragma unroll
        for (int n = 0; n < 4; ++n) acc[n] = fmaf(ss[n][k], w, acc[n]);
    }
#pragma unroll 4
    for (int k = 0; k < MM; ++k) {
        float w = Wout[(HH + k) * HH + j];
#pragma unroll
        for (int n = 0; n < 4; ++n) acc[n] = fmaf(hs[n][k], w, acc[n]);
    }
#pragma unroll
    for (int n = 0; n < 4; ++n) os[n][j] = acc[n];
    __syncthreads();

    float ck[10];
#pragma unroll
    for (int i = 0; i < 10; ++i) ck[i] = convk[i * HH];
    const float cb = convb[0];
#pragma unroll
    for (int n = 0; n < 4; ++n) {
        float y = cb;
#pragma unroll
        for (int i = 0; i < 10; ++i) {
            int p = j - 4 + i;
            float xv = (p >= 0 && p < HH) ? os[n][p] : 0.f;
            y = fmaf(xv, ck[i], y);
        }
        out[(size_t)(base + n) * HH + j] = y;
    }
    for (int idx = j; idx < 4 * MM; idx += 128) {
        int n = idx >> 6, c = idx & 63;
        out[(size_t)NN * HH + (size_t)(base + n) * MM + c] = hs[n][c];
    }
}

extern "C" void kernel_launch(void* const* d_in, const int* in_sizes, int n_in,
                              void* d_out, int out_size, void* d_ws, size_t ws_size,
                              hipStream_t stream) {
    const float* X    = (const float*)d_in[0];
    const int*   eraw = (const int*)d_in[1];
    const float* Wsp  = (const float*)d_in[2];
    const float* bsp  = (const float*)d_in[3];
    const float* Wmp  = (const float*)d_in[4];
    const float* bmp  = (const float*)d_in[5];
    const float* Wi   = (const float*)d_in[6];
    const float* bi   = (const float*)d_in[7];
    const float* Wh   = (const float*)d_in[8];
    const float* bhn  = (const float*)d_in[9];
    const float* Wout = (const float*)d_in[10];
    const float* bout = (const float*)d_in[11];
    const float* ck   = (const float*)d_in[12];
    const float* cb   = (const float*)d_in[13];
    float* out = (float*)d_out;

    float* ws = (float*)d_ws;
    float*    s_buf  = ws;                                   // N*128 fp32
    float*    a_all  = s_buf + (size_t)NN * 128;             // T*N*64 fp32
    unsigned short* qb_all = (unsigned short*)(a_all + (size_t)TT * NN * 64); // T*N*64 bf16
    unsigned* mihp   = (unsigned*)(qb_all + (size_t)TT * NN * 64);            // N*128 packed
    float*    bias_g = (float*)(mihp + (size_t)NN * 128);    // 256
    short*    Bp1    = (short*)(bias_g + 256);               // 32768 shorts
    short*    Bp2    = Bp1 + 8 * 4 * 2 * 512;                // 32768
    short*    Bp3    = Bp2 + 8 * 4 * 2 * 512;                // 65536
    int*      src     = (int*)(Bp3 + 16 * 4 * 2 * 512);
    int*      tgt     = src + EE;
    int*      csr_src = tgt + EE;
    int*      deg     = csr_src + EE;                        // N
    int*      rowptr  = deg + NN;                            // N+1
    int*      cursor  = rowptr + NN + 1;                     // N
    int*      itmp    = cursor + NN;                         // NBLK*256
    int*      bsum    = itmp + NBLK * 256;                   // 256
    int*      boffs   = bsum + 256;                          // 256

    hipMemsetAsync(mihp, 0, (size_t)NN * 128 * sizeof(unsigned), stream);  // h0 = 0
    hipMemsetAsync(deg, 0, NN * sizeof(int), stream);
    hipMemsetAsync(cursor, 0, NN * sizeof(int), stream);

    kConvEdges<<<(EE + 255) / 256, 256, 0, stream>>>(eraw, src, tgt, deg);
    kScanA<<<NBLK, 256, 0, stream>>>(deg, itmp, bsum);
    kScanB<<<1, 256, 0, stream>>>(bsum, boffs);
    kScanC<<<NBLK, 256, 0, stream>>>(itmp, boffs, rowptr);
    kFill<<<(EE + 255) / 256, 256, 0, stream>>>(src, tgt, rowptr, cursor, csr_src);
    kPrep<<<64, 256, 0, stream>>>(Wsp, Wmp, Wi, bi, Wh, bhn, Bp1, Bp2, Bp3, bias_g);

    // feed-forward for all T*N rows in one pass (400000 = 64 * 6250 exactly)
    kFF<<<(TT * NN) / 64, 256, 0, stream>>>(X, Bp1, bsp, Bp2, bmp, a_all, qb_all, s_buf);

    const int gx3 = (NN + 31) / 32;  // 1563
    for (int t = 0; t < TT; ++t) {
        kGatherB<<<(NN * 64 + 255) / 256, 256, 0, stream>>>(
            a_all + (size_t)t * NN * 64, qb_all + (size_t)t * NN * 64,
            rowptr, csr_src, mihp);
        kGemm3<<<gx3, 256, 0, stream>>>(mihp, Bp3, bias_g);
    }
    kD<<<NN / 4, 128, 0, stream>>>(s_buf, mihp, Wout, bout, ck, cb, out);
}